// Round 11
// baseline (172.459 us; speedup 1.0000x reference)
//
#include <hip/hip_runtime.h>

typedef _Float16 f16;
typedef __attribute__((ext_vector_type(2))) _Float16 f16x2;
typedef __attribute__((ext_vector_type(8))) _Float16 f16x8;
typedef __attribute__((ext_vector_type(4))) float f32x4;

#define MFMA16(a,b,c) __builtin_amdgcn_mfma_f32_16x16x32_f16(a,b,c,0,0,0)

constexpr int NSEQ = 64;    // 2*8*4
constexpr int P    = 256;   // tokens per sequence
constexpr int DIMF = 768;
constexpr int NH   = 12;
constexpr int DH   = 64;
constexpr int M    = NSEQ * P;        // 16384
constexpr size_t XSZ = (size_t)M * DIMF;
constexpr size_t WSZ = (size_t)DIMF * DIMF;

__device__ __forceinline__ f16x8 cvt8(const float* p) {
    const float4 u = *(const float4*)p;
    const float4 w = *(const float4*)(p + 4);
    f16x2 a = __builtin_bit_cast(f16x2, __builtin_amdgcn_cvt_pkrtz(u.x, u.y));
    f16x2 b = __builtin_bit_cast(f16x2, __builtin_amdgcn_cvt_pkrtz(u.z, u.w));
    f16x2 c = __builtin_bit_cast(f16x2, __builtin_amdgcn_cvt_pkrtz(w.x, w.y));
    f16x2 d = __builtin_bit_cast(f16x2, __builtin_amdgcn_cvt_pkrtz(w.z, w.w));
    f16x8 r;
    r[0]=a[0]; r[1]=a[1]; r[2]=b[0]; r[3]=b[1];
    r[4]=c[0]; r[5]=c[1]; r[6]=d[0]; r[7]=d[1];
    return r;
}

__device__ __forceinline__ void gload16(const void* g, void* l) {
    __builtin_amdgcn_global_load_lds(
        (const __attribute__((address_space(1))) void*)g,
        (__attribute__((address_space(3))) void*)l, 16, 0, 0);
}

// ---- fp32 -> fp16 convert ----
__global__ __launch_bounds__(256) void conv_kernel(
    const float* __restrict__ x,
    const float* __restrict__ Wq, const float* __restrict__ Wk,
    const float* __restrict__ Wv,
    f16* __restrict__ xh, f16* __restrict__ wh)
{
    const size_t i8 = ((size_t)blockIdx.x * 256 + threadIdx.x) * 8;
    if (i8 < XSZ) {
        *(f16x8*)(xh + i8) = cvt8(x + i8);
    } else {
        const size_t j = i8 - XSZ;
        const int mtx = (int)(j / WSZ);
        const size_t r = j - (size_t)mtx * WSZ;
        const float* src = (mtx == 0 ? Wq : mtx == 1 ? Wk : Wv) + r;
        *(f16x8*)(wh + j) = cvt8(src);
    }
}

// ---- projection GEMM: 256x256, BK=64, K = 768 -> 12 K-tiles.
// A: LDS double-buffer (2x32KB, chunk swizzle c^=row&7). B: fragments DIRECT
// from global (L2-resident panel) into registers — halves per-CU LDS traffic.
// Per K-tile: {b-loads || stage A(T+1)} -> vmcnt(12) -> barrier -> read/MFMA
// low -> read/MFMA high -> barrier. Compiler auto-scoreboards b-reg deps.
__global__ __launch_bounds__(512, 1) void proj_gemm(
    const f16* __restrict__ xh, const f16* __restrict__ wh,
    const float* __restrict__ bq, const float* __restrict__ bk,
    const float* __restrict__ bv,
    f16* __restrict__ qout, f16* __restrict__ kout, f16* __restrict__ vt)
{
    __shared__ __align__(16) char smem[67584];   // 2x32KB A bufs; epilogue reuse
    const int wg = (blockIdx.x & 7) * 72 + (blockIdx.x >> 3);   // bijective 576=8*72
    const int nt = wg % 9;
    const int mt = wg / 9;
    const int m0 = mt * 256, n0 = nt * 256;

    const int tid  = threadIdx.x;
    const int lane = tid & 63;
    const int wave = tid >> 6;
    const int lr   = lane & 15;
    const int lg   = lane >> 4;
    const int wm   = wave >> 2;       // 0..1 : 128-row half of tile
    const int wn   = wave & 3;        // 0..3 : 64-col strip

    // A staging: thread covers row (tid>>3)+64*r4, chunk (tid&7)^(row&7)
    const f16* srcA = xh + (size_t)(m0 + (tid >> 3)) * DIMF
                         + (((tid & 7) ^ ((tid >> 3) & 7)) * 8);
    // B per-lane base: col = n0 + wn*64 + n*16 + lr ; k = T*64 + kh*32 + lg*8
    const f16* srcB = wh + (size_t)(n0 + wn * 64 + lr) * DIMF + lg * 8;

    // A fragment reads (swizzle matches staging; row&7 == lr&7 for frag rows)
    const int swz0 = (lg ^ (lr & 7)) * 16;
    const char* pA0 = smem + (wm * 128 + lr) * 128;

    f32x4 acc[8][4];
    #pragma unroll
    for (int m = 0; m < 8; ++m)
        #pragma unroll
        for (int n = 0; n < 4; ++n) acc[m][n] = (f32x4){0.f,0.f,0.f,0.f};

    // prologue: stage A(0) -> buf0 (4 gloads/thread)
    #pragma unroll
    for (int r4 = 0; r4 < 4; ++r4)
        gload16(srcA + (size_t)(r4 * 64) * DIMF, smem + r4 * 8192 + tid * 16);

    f16x8 a[4][2], b[4][2];

    for (int T = 0; T < 12; ++T) {            // K = 768 = 12 x BK(64)
        // ---- b-fragment loads for tile T (regular loads; HW scoreboard) ----
        #pragma unroll
        for (int n = 0; n < 4; ++n)
            #pragma unroll
            for (int kh = 0; kh < 2; ++kh)
                b[n][kh] = *(const f16x8*)(srcB + (size_t)n * (16 * DIMF)
                                                + T * 64 + kh * 32);
        // ---- stage A(T+1) ----
        if (T < 11) {
            const f16* ga = srcA + (size_t)(T + 1) * 64;
            char* sA = smem + ((T + 1) & 1) * 32768;
            #pragma unroll
            for (int r4 = 0; r4 < 4; ++r4)
                gload16(ga + (size_t)(r4 * 64) * DIMF, sA + r4 * 8192 + tid * 16);
            // region holds 12 new VMEM ops (b8 + A4, any order); vmcnt(12)
            // retires exactly the pre-region survivors = tile T's A stages.
            asm volatile("s_waitcnt vmcnt(12)" ::: "memory");
        } else {
            asm volatile("s_waitcnt vmcnt(8)" ::: "memory");   // b8 only region
        }
        __builtin_amdgcn_s_barrier();            // publish A(T)
        __builtin_amdgcn_sched_barrier(0);

        const char* lA = pA0 + (T & 1) * 32768;
        // ---- low half: m-frags 0..3 ----
        #pragma unroll
        for (int m = 0; m < 4; ++m) {
            a[m][0] = *(const f16x8*)(lA + m * 2048 + swz0);
            a[m][1] = *(const f16x8*)(lA + m * 2048 + (swz0 ^ 64));
        }
        asm volatile("s_waitcnt lgkmcnt(0)" ::: "memory");
        __builtin_amdgcn_sched_barrier(0);
        __builtin_amdgcn_s_setprio(1);
        #pragma unroll
        for (int m = 0; m < 4; ++m)
            #pragma unroll
            for (int n = 0; n < 4; ++n) {
                acc[m][n] = MFMA16(a[m][0], b[n][0], acc[m][n]);
                acc[m][n] = MFMA16(a[m][1], b[n][1], acc[m][n]);
            }
        __builtin_amdgcn_s_setprio(0);
        // ---- high half: m-frags 4..7 ----
        #pragma unroll
        for (int m = 0; m < 4; ++m) {
            a[m][0] = *(const f16x8*)(lA + (4 + m) * 2048 + swz0);
            a[m][1] = *(const f16x8*)(lA + (4 + m) * 2048 + (swz0 ^ 64));
        }
        asm volatile("s_waitcnt lgkmcnt(0)" ::: "memory");
        __builtin_amdgcn_sched_barrier(0);
        __builtin_amdgcn_s_setprio(1);
        #pragma unroll
        for (int m = 0; m < 4; ++m)
            #pragma unroll
            for (int n = 0; n < 4; ++n) {
                acc[4 + m][n] = MFMA16(a[m][0], b[n][0], acc[4 + m][n]);
                acc[4 + m][n] = MFMA16(a[m][1], b[n][1], acc[4 + m][n]);
            }
        __builtin_amdgcn_s_setprio(0);
        __builtin_amdgcn_s_barrier();            // WAR guard for next stages
    }

    __syncthreads();

    // ---- epilogue: 2-pass LDS bounce (pass hh = 128-row half) ----
    const int mat = nt / 3;               // 0=q 1=k 2=v
    const int c0  = (nt % 3) * 256;
    const int seq = mt;
    const float* __restrict__ bias = mat == 0 ? bq : mat == 1 ? bk : bv;
    float bv4[4];
    #pragma unroll
    for (int n = 0; n < 4; ++n) bv4[n] = bias[c0 + wn*64 + n*16 + lr];

    f16 (*ep)[264] = (f16 (*)[264])smem;
    #pragma unroll
    for (int hh = 0; hh < 2; ++hh) {
        if (wm == hh) {
            #pragma unroll
            for (int m = 0; m < 8; ++m)
                #pragma unroll
                for (int n = 0; n < 4; ++n)
                    #pragma unroll
                    for (int i = 0; i < 4; ++i)
                        ep[m*16 + lg*4 + i][wn*64 + n*16 + lr] =
                            (f16)(acc[m][n][i] + bv4[n]);
        }
        __syncthreads();
        if (mat < 2) {
            f16* __restrict__ dst = mat ? kout : qout;
            const int r = tid >> 2;
            #pragma unroll
            for (int s = 0; s < 8; ++s) {
                const int ch = s*4 + (tid & 3);
                const int h  = (nt % 3) * 4 + (ch >> 3);
                const int d0 = (ch & 7) * 8;
                *(f16x8*)(dst + ((size_t)(seq*NH + h)*P + hh*128 + r)*DH + d0) =
                    *(const f16x8*)&ep[r][ch*8];
            }
        } else {
            const int col = tid >> 1, rg = tid & 1;
            const int h = (nt % 3) * 4 + (col >> 6), d = col & 63;
            f16* drow = vt + ((size_t)(seq*NH + h)*DH + d)*P + hh*128 + rg*64;
            #pragma unroll
            for (int u = 0; u < 8; ++u) {
                f16x8 vv;
                #pragma unroll
                for (int uu = 0; uu < 8; ++uu)
                    vv[uu] = ep[rg*64 + u*8 + uu][col];
                *(f16x8*)(drow + u*8) = vv;
            }
        }
        __syncthreads();
    }
}

// ---- attention (unchanged from passing round 5) ----
__global__ __launch_bounds__(512) void attn_kernel(
    const f16* __restrict__ q, const f16* __restrict__ k,
    const f16* __restrict__ vt, float* __restrict__ out)
{
    __shared__ __align__(16) char kl[32768];
    __shared__ __align__(16) char vl[32768];
    __shared__ __align__(16) char pl[8][2048];

    const int n = blockIdx.x;                    // 1536 = 8 * 192
    const int b = (n & 7) * 192 + (n >> 3);
    const int half = b & 1;
    const int head = (b >> 1) % NH;
    const int seq  = b / (2 * NH);

    const int tid  = threadIdx.x;
    const int lane = tid & 63;
    const int wave = tid >> 6;
    const int lr   = lane & 15;
    const int lg   = lane >> 4;

    const f16* qh = q  + (size_t)(seq*NH + head)*P*DH;
    const f16* kh = k  + (size_t)(seq*NH + head)*P*DH;
    const f16* vh = vt + (size_t)(seq*NH + head)*DH*P;

    {
        const int r0 = tid >> 3, ck = tid & 7;
        const int d0 = tid >> 5, cv = tid & 31;
        #pragma unroll
        for (int it = 0; it < 4; ++it) {
            const int row = it * 64 + r0;
            gload16(kh + row * 64 + ((ck ^ (row & 7)) * 8), kl + it * 8192 + tid * 16);
            const int d = it * 16 + d0;
            gload16(vh + d * 256 + (((cv & 24) | ((cv ^ d) & 7)) * 8), vl + it * 8192 + tid * 16);
        }
    }

    const int qr0 = half * 128 + wave * 16;
    const f16x8 aq0 = *(const f16x8*)(qh + (qr0 + lr) * DH + lg * 8);
    const f16x8 aq1 = *(const f16x8*)(qh + (qr0 + lr) * DH + 32 + lg * 8);

    __syncthreads();

    f32x4 s[16];
    #pragma unroll
    for (int t = 0; t < 16; ++t) s[t] = (f32x4){0.f,0.f,0.f,0.f};
    #pragma unroll
    for (int t = 0; t < 16; ++t) {
        const int row = t * 16 + lr;
        const f16x8 b0 = *(const f16x8*)(kl + row * 128 + ((lg ^ (row & 7)) * 16));
        const f16x8 b1 = *(const f16x8*)(kl + row * 128 + (((lg + 4) ^ (row & 7)) * 16));
        s[t] = MFMA16(aq0, b0, s[t]);
        s[t] = MFMA16(aq1, b1, s[t]);
    }

    float mx[4] = {-1e30f, -1e30f, -1e30f, -1e30f};
    #pragma unroll
    for (int t = 0; t < 16; ++t)
        #pragma unroll
        for (int i = 0; i < 4; ++i) mx[i] = fmaxf(mx[i], s[t][i]);
    #pragma unroll
    for (int st = 1; st < 16; st <<= 1)
        #pragma unroll
        for (int i = 0; i < 4; ++i) mx[i] = fmaxf(mx[i], __shfl_xor(mx[i], st));

    const float SCL = 0.125f * 1.44269504088896f;
    float rs[4] = {0.f, 0.f, 0.f, 0.f};
    #pragma unroll
    for (int t = 0; t < 16; ++t)
        #pragma unroll
        for (int i = 0; i < 4; ++i) {
            const float e = exp2f((s[t][i] - mx[i]) * SCL);
            s[t][i] = e;
            rs[i] += e;
        }
    #pragma unroll
    for (int st = 1; st < 16; st <<= 1)
        #pragma unroll
        for (int i = 0; i < 4; ++i) rs[i] += __shfl_xor(rs[i], st);

    char* pw = pl[wave];
    f32x4 o[4];
    #pragma unroll
    for (int t = 0; t < 4; ++t) o[t] = (f32x4){0.f,0.f,0.f,0.f};

    #pragma unroll
    for (int qq = 0; qq < 4; ++qq) {
        #pragma unroll
        for (int tt = 0; tt < 4; ++tt) {
            const int t = qq * 4 + tt;
            #pragma unroll
            for (int i = 0; i < 4; ++i) {
                const int r = lg * 4 + i;
                const int klocal = tt * 16 + lr;
                *(f16*)(pw + r * 128 + ((klocal * 2) ^ ((r & 7) << 4))) = (f16)s[t][i];
            }
        }
        #pragma unroll
        for (int kol = 0; kol < 2; ++kol) {
            const f16x8 ap = *(const f16x8*)(pw + lr * 128 + (((kol * 4 + lg) ^ (lr & 7)) * 16));
            #pragma unroll
            for (int dt = 0; dt < 4; ++dt) {
                const int row = dt * 16 + lr;
                const int ch  = qq * 8 + kol * 4 + lg;
                const f16x8 bv_ = *(const f16x8*)(vl + row * 512 + (((ch & 24) | ((ch ^ row) & 7)) * 16));
                o[dt] = MFMA16(ap, bv_, o[dt]);
            }
        }
    }

    #pragma unroll
    for (int i = 0; i < 4; ++i) rs[i] = 1.f / rs[i];
    float* op = out + ((size_t)seq * P + qr0) * DIMF + head * DH;
    #pragma unroll
    for (int t = 0; t < 4; ++t)
        #pragma unroll
        for (int i = 0; i < 4; ++i)
            op[(lg * 4 + i) * DIMF + t * 16 + lr] = o[t][i] * rs[i];
}

extern "C" void kernel_launch(void* const* d_in, const int* in_sizes, int n_in,
                              void* d_out, int out_size, void* d_ws, size_t ws_size,
                              hipStream_t stream) {
    const float* x  = (const float*)d_in[0];
    const float* Wq = (const float*)d_in[1];
    const float* bq = (const float*)d_in[2];
    const float* Wk = (const float*)d_in[3];
    const float* bk = (const float*)d_in[4];
    const float* Wv = (const float*)d_in[5];
    const float* bv = (const float*)d_in[6];
    float* out = (float*)d_out;

    f16* xh = (f16*)d_out;          // fp16 staging lives in d_out (fully consumed
    f16* wh = xh + XSZ;             // by proj_gemm before attn overwrites d_out)

    const size_t QSZ = (size_t)M * DIMF;
    f16* q  = (f16*)d_ws;
    f16* k  = q + QSZ;
    f16* vt = k + QSZ;

    const int convThreads = (int)((XSZ + 3 * WSZ) / 8);
    conv_kernel<<<convThreads / 256, 256, 0, stream>>>(x, Wq, Wk, Wv, xh, wh);
    proj_gemm<<<dim3(576), 512, 0, stream>>>(xh, wh, bq, bk, bv, q, k, vt);
    attn_kernel<<<dim3(NSEQ * NH * 2), 512, 0, stream>>>(q, k, vt, out);
}

// Round 13
// 129.702 us; speedup vs baseline: 1.3297x; 1.3297x over previous
//
#include <hip/hip_runtime.h>

typedef _Float16 f16;
typedef __attribute__((ext_vector_type(2))) _Float16 f16x2;
typedef __attribute__((ext_vector_type(8))) _Float16 f16x8;
typedef __attribute__((ext_vector_type(4))) float f32x4;

#define MFMA16(a,b,c) __builtin_amdgcn_mfma_f32_16x16x32_f16(a,b,c,0,0,0)

constexpr int NSEQ = 64;    // 2*8*4
constexpr int P    = 256;   // tokens per sequence
constexpr int DIMF = 768;
constexpr int NH   = 12;
constexpr int DH   = 64;
constexpr int M    = NSEQ * P;        // 16384
constexpr size_t XSZ = (size_t)M * DIMF;
constexpr size_t WSZ = (size_t)DIMF * DIMF;

__device__ __forceinline__ f16x8 cvt8(const float* p) {
    const float4 u = *(const float4*)p;
    const float4 w = *(const float4*)(p + 4);
    f16x2 a = __builtin_bit_cast(f16x2, __builtin_amdgcn_cvt_pkrtz(u.x, u.y));
    f16x2 b = __builtin_bit_cast(f16x2, __builtin_amdgcn_cvt_pkrtz(u.z, u.w));
    f16x2 c = __builtin_bit_cast(f16x2, __builtin_amdgcn_cvt_pkrtz(w.x, w.y));
    f16x2 d = __builtin_bit_cast(f16x2, __builtin_amdgcn_cvt_pkrtz(w.z, w.w));
    f16x8 r;
    r[0]=a[0]; r[1]=a[1]; r[2]=b[0]; r[3]=b[1];
    r[4]=c[0]; r[5]=c[1]; r[6]=d[0]; r[7]=d[1];
    return r;
}

__device__ __forceinline__ void gload16(const void* g, void* l) {
    __builtin_amdgcn_global_load_lds(
        (const __attribute__((address_space(1))) void*)g,
        (__attribute__((address_space(3))) void*)l, 16, 0, 0);
}

// ---- fp32 -> fp16 convert ----
__global__ __launch_bounds__(256) void conv_kernel(
    const float* __restrict__ x,
    const float* __restrict__ Wq, const float* __restrict__ Wk,
    const float* __restrict__ Wv,
    f16* __restrict__ xh, f16* __restrict__ wh)
{
    const size_t i8 = ((size_t)blockIdx.x * 256 + threadIdx.x) * 8;
    if (i8 < XSZ) {
        *(f16x8*)(xh + i8) = cvt8(x + i8);
    } else {
        const size_t j = i8 - XSZ;
        const int mtx = (int)(j / WSZ);
        const size_t r = j - (size_t)mtx * WSZ;
        const float* src = (mtx == 0 ? Wq : mtx == 1 ? Wk : Wv) + r;
        *(f16x8*)(wh + j) = cvt8(src);
    }
}

// ---- projection GEMM, 256x256 tile, BK=64, 8 waves (2M x 4N), 4-phase,
// need-ordered quarter-unit staging + 2 counted vmcnt per K-tile.
// Units Aq0..3 / Bq0..3 = 64 rows each (1 gload/thread).
// Placement: ph0 {Aq0,Bq0}(T+1) ph1 {Bq1} ph2 {Aq2} ph3 {Bq2,Bq3 | Aq1,Aq3}.
// Ledger (per-wave FIFO, induction-verified):
//  @ph0(T): queue = [Aq0..Aq2(T) 4units, Bq2,Bq3(T), Aq1,Aq3(T), Aq0,Bq0(T+1)]
//           vmcnt(4) -> complete: ALL tile-T units except Aq1,Aq3.
//  @ph2(T): after +Bq1(T+1),Aq2(T+1): 6 outstanding; vmcnt(4) -> Aq1,Aq3(T) done.
// Barriers: top (WAR), ph0, ph2 (publish). Tail: vmcnt(2)@ph0(11), 0@ph2(11).
// Persistent grid 256, XCD-chunked wg-loop over 576 tiles.
__global__ __launch_bounds__(512, 1) void proj_gemm(
    const f16* __restrict__ xh, const f16* __restrict__ wh,
    const float* __restrict__ bq, const float* __restrict__ bk,
    const float* __restrict__ bv,
    f16* __restrict__ qout, f16* __restrict__ kout, f16* __restrict__ vt)
{
    __shared__ __align__(16) char smem[131072];
    const int tid  = threadIdx.x;
    const int lane = tid & 63;
    const int wave = tid >> 6;
    const int lr   = lane & 15;
    const int lg   = lane >> 4;
    const int wm   = wave >> 2;       // 0..1  (128-row half)
    const int wn   = wave & 3;        // 0..3  (64-col strip)

    const int swz0 = (lg ^ (lr & 7)) * 16;
    const char* pA0 = smem + (wm * 128 + lr) * 128;
    const char* pB0 = smem + 65536 + (wn * 64 + lr) * 128;

    const int bid = (blockIdx.x & 7) * 32 + (blockIdx.x >> 3);   // XCD-chunked

    #define BAR  __builtin_amdgcn_s_barrier()
    #define LGKM asm volatile("s_waitcnt lgkmcnt(0)" ::: "memory")
    #define SCHB __builtin_amdgcn_sched_barrier(0)

    for (int wg = bid; wg < 576; wg += 256) {
        const int nt = wg % 9;
        const int mt = wg / 9;
        const int m0 = mt * 256, n0 = nt * 256;

        const int srow = tid >> 3, scc = tid & 7;
        const f16* gA = xh + (size_t)(m0 + srow) * DIMF + (scc ^ (srow & 7)) * 8;
        const f16* gB = wh + (size_t)(n0 + srow) * DIMF + (scc ^ (srow & 7)) * 8;

        f32x4 acc[8][4];
        #pragma unroll
        for (int f = 0; f < 8; ++f)
            #pragma unroll
            for (int g = 0; g < 4; ++g) acc[f][g] = (f32x4){0.f,0.f,0.f,0.f};

        // ---- prologue: tile 0 in NEED order: [Aq0,Bq0,Bq1,Bq2,Bq3,Aq2 | Aq1,Aq3]
        gload16(gA,                        smem + 0*8192  + tid*16);          // Aq0
        gload16(gB,                        smem + 65536 + 0*8192 + tid*16);   // Bq0
        gload16(gB + (size_t)( 64*DIMF),   smem + 65536 + 1*8192 + tid*16);   // Bq1
        gload16(gB + (size_t)(128*DIMF),   smem + 65536 + 2*8192 + tid*16);   // Bq2
        gload16(gB + (size_t)(192*DIMF),   smem + 65536 + 3*8192 + tid*16);   // Bq3
        gload16(gA + (size_t)(128*DIMF),   smem + 2*8192  + tid*16);          // Aq2
        SCHB;
        gload16(gA + (size_t)( 64*DIMF),   smem + 1*8192  + tid*16);          // Aq1
        gload16(gA + (size_t)(192*DIMF),   smem + 3*8192  + tid*16);          // Aq3

        f16x8 a[4][2], bf[2][2];

        for (int kt = 0; kt < 12; ++kt) {
            const int b = kt & 1;
            const char* lA = pA0 + b * 32768;
            const char* lB = pB0 + b * 32768;
            char* sA = smem + (b ^ 1) * 32768;
            char* sB = sA + 65536;
            const f16* ga = gA + (kt + 1) * 64;
            const f16* gb = gB + (kt + 1) * 64;
            const bool st = kt < 11;

            BAR;   // WAR: all waves done reading buf b^1 (tile kt-1) before staging

            // ---- phase 0: stage Aq0,Bq0(T+1); vmcnt; publish; (A-low x B-low)
            if (st) { gload16(ga, sA + tid*16); gload16(gb, sB + tid*16); }
            SCHB;
            if (st) asm volatile("s_waitcnt vmcnt(4)" ::: "memory");
            else    asm volatile("s_waitcnt vmcnt(2)" ::: "memory");
            BAR;
            SCHB;
            #pragma unroll
            for (int f = 0; f < 4; ++f) {
                a[f][0] = *(const f16x8*)(lA + f*2048 + swz0);
                a[f][1] = *(const f16x8*)(lA + f*2048 + (swz0 ^ 64));
            }
            #pragma unroll
            for (int f = 0; f < 2; ++f) {
                bf[f][0] = *(const f16x8*)(lB + f*2048 + swz0);
                bf[f][1] = *(const f16x8*)(lB + f*2048 + (swz0 ^ 64));
            }
            LGKM; SCHB;
            __builtin_amdgcn_s_setprio(1);
            #pragma unroll
            for (int f = 0; f < 4; ++f)
                #pragma unroll
                for (int g = 0; g < 2; ++g) {
                    acc[f][g] = MFMA16(a[f][0], bf[g][0], acc[f][g]);
                    acc[f][g] = MFMA16(a[f][1], bf[g][1], acc[f][g]);
                }
            __builtin_amdgcn_s_setprio(0);

            // ---- phase 1: stage Bq1(T+1); (A-low x B-high) — data already pub.
            if (st) gload16(gb + (size_t)(64*DIMF), sB + 8192 + tid*16);
            #pragma unroll
            for (int f = 0; f < 2; ++f) {
                bf[f][0] = *(const f16x8*)(lB + (2+f)*2048 + swz0);
                bf[f][1] = *(const f16x8*)(lB + (2+f)*2048 + (swz0 ^ 64));
            }
            LGKM; SCHB;
            __builtin_amdgcn_s_setprio(1);
            #pragma unroll
            for (int f = 0; f < 4; ++f)
                #pragma unroll
                for (int g = 0; g < 2; ++g) {
                    acc[f][2+g] = MFMA16(a[f][0], bf[g][0], acc[f][2+g]);
                    acc[f][2+g] = MFMA16(a[f][1], bf[g][1], acc[f][2+g]);
                }
            __builtin_amdgcn_s_setprio(0);

            // ---- phase 2: stage Aq2(T+1); vmcnt retires Aq1,Aq3(T); publish;
            //      (A-high x B-high)
            if (st) gload16(ga + (size_t)(128*DIMF), sA + 16384 + tid*16);
            SCHB;
            if (st) asm volatile("s_waitcnt vmcnt(4)" ::: "memory");
            else    asm volatile("s_waitcnt vmcnt(0)" ::: "memory");
            BAR;
            SCHB;
            #pragma unroll
            for (int f = 0; f < 4; ++f) {
                a[f][0] = *(const f16x8*)(lA + (4+f)*2048 + swz0);
                a[f][1] = *(const f16x8*)(lA + (4+f)*2048 + (swz0 ^ 64));
            }
            LGKM; SCHB;
            __builtin_amdgcn_s_setprio(1);
            #pragma unroll
            for (int f = 0; f < 4; ++f)
                #pragma unroll
                for (int g = 0; g < 2; ++g) {
                    acc[4+f][2+g] = MFMA16(a[f][0], bf[g][0], acc[4+f][2+g]);
                    acc[4+f][2+g] = MFMA16(a[f][1], bf[g][1], acc[4+f][2+g]);
                }
            __builtin_amdgcn_s_setprio(0);

            // ---- phase 3: stage Bq2,Bq3 then Aq1,Aq3 (T+1), A's LAST;
            //      (A-high x B-low re-read, tile-T data long published)
            if (st) {
                gload16(gb + (size_t)(128*DIMF), sB + 16384 + tid*16);
                gload16(gb + (size_t)(192*DIMF), sB + 24576 + tid*16);
                SCHB;
                gload16(ga + (size_t)( 64*DIMF), sA + 8192  + tid*16);
                gload16(ga + (size_t)(192*DIMF), sA + 24576 + tid*16);
            }
            #pragma unroll
            for (int f = 0; f < 2; ++f) {
                bf[f][0] = *(const f16x8*)(lB + f*2048 + swz0);
                bf[f][1] = *(const f16x8*)(lB + f*2048 + (swz0 ^ 64));
            }
            LGKM; SCHB;
            __builtin_amdgcn_s_setprio(1);
            #pragma unroll
            for (int f = 0; f < 4; ++f)
                #pragma unroll
                for (int g = 0; g < 2; ++g) {
                    acc[4+f][g] = MFMA16(a[f][0], bf[g][0], acc[4+f][g]);
                    acc[4+f][g] = MFMA16(a[f][1], bf[g][1], acc[4+f][g]);
                }
            __builtin_amdgcn_s_setprio(0);
        }

        __syncthreads();

        // ---- epilogue: 2-pass LDS bounce (128 rows x 256 cols per pass) ----
        const int mat = nt / 3;               // 0=q 1=k 2=v
        const int c0  = (nt % 3) * 256;
        const int seq = mt;
        const float* __restrict__ bias = mat == 0 ? bq : mat == 1 ? bk : bv;
        float bb[4];
        #pragma unroll
        for (int g = 0; g < 4; ++g) bb[g] = bias[c0 + wn*64 + g*16 + lr];

        f16 (*ep)[264] = (f16 (*)[264])smem;
        #pragma unroll
        for (int hh = 0; hh < 2; ++hh) {
            if (wm == hh) {
                #pragma unroll
                for (int f = 0; f < 8; ++f)
                    #pragma unroll
                    for (int g = 0; g < 4; ++g)
                        #pragma unroll
                        for (int i = 0; i < 4; ++i)
                            ep[f*16 + lg*4 + i][wn*64 + g*16 + lr] =
                                (f16)(acc[f][g][i] + bb[g]);
            }
            __syncthreads();
            if (mat < 2) {
                f16* __restrict__ dst = mat ? kout : qout;
                const int r = tid >> 2;
                #pragma unroll
                for (int s = 0; s < 8; ++s) {
                    const int ch = s*4 + (tid & 3);
                    const int h  = (nt % 3) * 4 + (ch >> 3);
                    const int d0 = (ch & 7) * 8;
                    *(f16x8*)(dst + ((size_t)(seq*NH + h)*P + hh*128 + r)*DH + d0) =
                        *(const f16x8*)&ep[r][ch*8];
                }
            } else {
                const int col = tid >> 1, rg = tid & 1;
                const int h = (nt % 3) * 4 + (col >> 6), d = col & 63;
                f16* drow = vt + ((size_t)(seq*NH + h)*DH + d)*P + hh*128 + rg*64;
                #pragma unroll
                for (int u = 0; u < 8; ++u) {
                    f16x8 vv;
                    #pragma unroll
                    for (int uu = 0; uu < 8; ++uu)
                        vv[uu] = ep[rg*64 + u*8 + uu][col];
                    *(f16x8*)(drow + u*8) = vv;
                }
            }
            __syncthreads();
        }
    }
    #undef BAR
    #undef LGKM
    #undef SCHB
}

// ---- attention (unchanged from passing round 5) ----
__global__ __launch_bounds__(512) void attn_kernel(
    const f16* __restrict__ q, const f16* __restrict__ k,
    const f16* __restrict__ vt, float* __restrict__ out)
{
    __shared__ __align__(16) char kl[32768];
    __shared__ __align__(16) char vl[32768];
    __shared__ __align__(16) char pl[8][2048];

    const int n = blockIdx.x;                    // 1536 = 8 * 192
    const int b = (n & 7) * 192 + (n >> 3);
    const int half = b & 1;
    const int head = (b >> 1) % NH;
    const int seq  = b / (2 * NH);

    const int tid  = threadIdx.x;
    const int lane = tid & 63;
    const int wave = tid >> 6;
    const int lr   = lane & 15;
    const int lg   = lane >> 4;

    const f16* qh = q  + (size_t)(seq*NH + head)*P*DH;
    const f16* kh = k  + (size_t)(seq*NH + head)*P*DH;
    const f16* vh = vt + (size_t)(seq*NH + head)*DH*P;

    {
        const int r0 = tid >> 3, ck = tid & 7;
        const int d0 = tid >> 5, cv = tid & 31;
        #pragma unroll
        for (int it = 0; it < 4; ++it) {
            const int row = it * 64 + r0;
            gload16(kh + row * 64 + ((ck ^ (row & 7)) * 8), kl + it * 8192 + tid * 16);
            const int d = it * 16 + d0;
            gload16(vh + d * 256 + (((cv & 24) | ((cv ^ d) & 7)) * 8), vl + it * 8192 + tid * 16);
        }
    }

    const int qr0 = half * 128 + wave * 16;
    const f16x8 aq0 = *(const f16x8*)(qh + (qr0 + lr) * DH + lg * 8);
    const f16x8 aq1 = *(const f16x8*)(qh + (qr0 + lr) * DH + 32 + lg * 8);

    __syncthreads();

    f32x4 s[16];
    #pragma unroll
    for (int t = 0; t < 16; ++t) s[t] = (f32x4){0.f,0.f,0.f,0.f};
    #pragma unroll
    for (int t = 0; t < 16; ++t) {
        const int row = t * 16 + lr;
        const f16x8 b0 = *(const f16x8*)(kl + row * 128 + ((lg ^ (row & 7)) * 16));
        const f16x8 b1 = *(const f16x8*)(kl + row * 128 + (((lg + 4) ^ (row & 7)) * 16));
        s[t] = MFMA16(aq0, b0, s[t]);
        s[t] = MFMA16(aq1, b1, s[t]);
    }

    float mx[4] = {-1e30f, -1e30f, -1e30f, -1e30f};
    #pragma unroll
    for (int t = 0; t < 16; ++t)
        #pragma unroll
        for (int i = 0; i < 4; ++i) mx[i] = fmaxf(mx[i], s[t][i]);
    #pragma unroll
    for (int st = 1; st < 16; st <<= 1)
        #pragma unroll
        for (int i = 0; i < 4; ++i) mx[i] = fmaxf(mx[i], __shfl_xor(mx[i], st));

    const float SCL = 0.125f * 1.44269504088896f;
    float rs[4] = {0.f, 0.f, 0.f, 0.f};
    #pragma unroll
    for (int t = 0; t < 16; ++t)
        #pragma unroll
        for (int i = 0; i < 4; ++i) {
            const float e = exp2f((s[t][i] - mx[i]) * SCL);
            s[t][i] = e;
            rs[i] += e;
        }
    #pragma unroll
    for (int st = 1; st < 16; st <<= 1)
        #pragma unroll
        for (int i = 0; i < 4; ++i) rs[i] += __shfl_xor(rs[i], st);

    char* pw = pl[wave];
    f32x4 o[4];
    #pragma unroll
    for (int t = 0; t < 4; ++t) o[t] = (f32x4){0.f,0.f,0.f,0.f};

    #pragma unroll
    for (int qq = 0; qq < 4; ++qq) {
        #pragma unroll
        for (int tt = 0; tt < 4; ++tt) {
            const int t = qq * 4 + tt;
            #pragma unroll
            for (int i = 0; i < 4; ++i) {
                const int r = lg * 4 + i;
                const int klocal = tt * 16 + lr;
                *(f16*)(pw + r * 128 + ((klocal * 2) ^ ((r & 7) << 4))) = (f16)s[t][i];
            }
        }
        #pragma unroll
        for (int kol = 0; kol < 2; ++kol) {
            const f16x8 ap = *(const f16x8*)(pw + lr * 128 + (((kol * 4 + lg) ^ (lr & 7)) * 16));
            #pragma unroll
            for (int dt = 0; dt < 4; ++dt) {
                const int row = dt * 16 + lr;
                const int ch  = qq * 8 + kol * 4 + lg;
                const f16x8 bv_ = *(const f16x8*)(vl + row * 512 + (((ch & 24) | ((ch ^ row) & 7)) * 16));
                o[dt] = MFMA16(ap, bv_, o[dt]);
            }
        }
    }

    #pragma unroll
    for (int i = 0; i < 4; ++i) rs[i] = 1.f / rs[i];
    float* op = out + ((size_t)seq * P + qr0) * DIMF + head * DH;
    #pragma unroll
    for (int t = 0; t < 4; ++t)
        #pragma unroll
        for (int i = 0; i < 4; ++i)
            op[(lg * 4 + i) * DIMF + t * 16 + lr] = o[t][i] * rs[i];
}

extern "C" void kernel_launch(void* const* d_in, const int* in_sizes, int n_in,
                              void* d_out, int out_size, void* d_ws, size_t ws_size,
                              hipStream_t stream) {
    const float* x  = (const float*)d_in[0];
    const float* Wq = (const float*)d_in[1];
    const float* bq = (const float*)d_in[2];
    const float* Wk = (const float*)d_in[3];
    const float* bk = (const float*)d_in[4];
    const float* Wv = (const float*)d_in[5];
    const float* bv = (const float*)d_in[6];
    float* out = (float*)d_out;

    f16* xh = (f16*)d_out;          // fp16 staging lives in d_out (fully consumed
    f16* wh = xh + XSZ;             // by proj_gemm before attn overwrites d_out)

    const size_t QSZ = (size_t)M * DIMF;
    f16* q  = (f16*)d_ws;
    f16* k  = q + QSZ;
    f16* vt = k + QSZ;

    const int convThreads = (int)((XSZ + 3 * WSZ) / 8);
    conv_kernel<<<convThreads / 256, 256, 0, stream>>>(x, Wq, Wk, Wv, xh, wh);
    proj_gemm<<<dim3(256), 512, 0, stream>>>(xh, wh, bq, bk, bv, q, k, vt);
    attn_kernel<<<dim3(NSEQ * NH * 2), 512, 0, stream>>>(q, k, vt, out);
}